// Round 12
// baseline (238.932 us; speedup 1.0000x reference)
//
#include <hip/hip_runtime.h>
#include <hip/hip_bf16.h>

using bf16 = __hip_bfloat16;
typedef __attribute__((ext_vector_type(8))) short s16x8;   // 8 bf16 = 4 VGPRs
typedef __attribute__((ext_vector_type(4))) float f32x4;

// ---- async global->LDS 16B copy (wave-uniform LDS base + lane*16) ----
__device__ __forceinline__ void async_cp16(const void* g, void* lds) {
    __builtin_amdgcn_global_load_lds(
        (const __attribute__((address_space(1))) unsigned int*)g,
        (__attribute__((address_space(3))) unsigned int*)lds,
        16, 0, 0);
}

__device__ __forceinline__ void storeC(float* p, float v) { *p = v; }
__device__ __forceinline__ void storeC(bf16* p, float v) { *p = __float2bfloat16(v); }

// pack 8 f32 -> s16x8 bf16 fragment
__device__ __forceinline__ s16x8 pack8(float4 a, float4 b) {
    union { bf16 h[8]; s16x8 v; } o;
    o.h[0] = __float2bfloat16(a.x); o.h[1] = __float2bfloat16(a.y);
    o.h[2] = __float2bfloat16(a.z); o.h[3] = __float2bfloat16(a.w);
    o.h[4] = __float2bfloat16(b.x); o.h[5] = __float2bfloat16(b.y);
    o.h[6] = __float2bfloat16(b.z); o.h[7] = __float2bfloat16(b.w);
    return o.v;
}

// ---------------------------------------------------------------------------
// prep: y=0: WkT[384,1024] = [Wk_w^T ; Wk_b ; 0]
//       y=1: WqT[256,1024] = Wq_w^T
//       y=2: WvT[384,1024] = [Wv_w^T ; Wv_b ; 0]
//       y=3: linb[256,1024] = bf16(lin_w)   y=4: zero csm (16384 f32)
// ---------------------------------------------------------------------------
__global__ __launch_bounds__(256) void prep_kernel(
    const float* __restrict__ Wk_w, const float* __restrict__ Wk_b,
    const float* __restrict__ Wq_w,
    const float* __restrict__ Wv_w, const float* __restrict__ Wv_b,
    const float* __restrict__ lin_w,
    bf16* __restrict__ WkT, bf16* __restrict__ WqT, bf16* __restrict__ WvT,
    bf16* __restrict__ linb, float* __restrict__ csm)
{
    const int t = threadIdx.x, b = blockIdx.x, y = blockIdx.y;
    if (y <= 2) {
        const float* src = (y == 0) ? Wk_w : (y == 1) ? Wq_w : Wv_w;
        const float* bia = (y == 0) ? Wk_b : Wv_b;
        bf16* dst = (y == 0) ? WkT : (y == 1) ? WqT : WvT;
        if (b < 64) {                       // 64x64 transpose tiles (16 x 4)
            __shared__ float T[64][65];
            const int h0 = (b & 15) * 64, d0 = (b >> 4) * 64;
            const int r = t >> 2, cg = t & 3;
            const float* sp = src + (h0 + r) * 256 + d0 + cg * 16;
#pragma unroll
            for (int c4 = 0; c4 < 4; ++c4) {
                float4 v = *(const float4*)(sp + c4 * 4);
                const int cb = cg * 16 + c4 * 4;
                T[cb + 0][r] = v.x; T[cb + 1][r] = v.y;
                T[cb + 2][r] = v.z; T[cb + 3][r] = v.w;
            }
            __syncthreads();
            union { bf16 h[16]; uint4 u[2]; } o;
#pragma unroll
            for (int j = 0; j < 16; ++j) o.h[j] = __float2bfloat16(T[r][cg * 16 + j]);
            uint4* dp = (uint4*)(dst + (size_t)(d0 + r) * 1024 + h0 + cg * 16);
            dp[0] = o.u[0]; dp[1] = o.u[1];
        } else if (y != 1) {
            if (b < 68) {                   // row 256 = bias
                const int i = (b - 64) * 256 + t;
                dst[256 * 1024 + i] = __float2bfloat16(bia[i]);
            } else if (b < 132) {           // rows 257..383 = 0
                const int i = (b - 68) * 256 + t;
                if (i < 127 * 1024 / 8)
                    ((uint4*)(dst + 257 * 1024))[i] = uint4{0, 0, 0, 0};
            }
        }
    } else if (y == 3) {
        const int i = b * 256 + t;          // 65536 float4 groups
        float4 v = ((const float4*)lin_w)[i];
        union { bf16 h[4]; uint2 u; } o;
        o.h[0] = __float2bfloat16(v.x); o.h[1] = __float2bfloat16(v.y);
        o.h[2] = __float2bfloat16(v.z); o.h[3] = __float2bfloat16(v.w);
        ((uint2*)linb)[i] = o.u;
    } else {
        const int i = b * 256 + t;
        if (i < 4096) ((float4*)csm)[i] = float4{0.f, 0.f, 0.f, 0.f};
    }
}

// ---------------------------------------------------------------------------
// NT GEMM: C[M,N] = scale * (A[M,K] @ B[N,K]^T) + bias
//   Tile (TM*32)xBN, BK=64, 256 threads (4 waves), XOR-swizzled LDS
//   TM: m-frags per wave (4 -> 128-row tile, 8 -> 256-row tile)
//   BIAS: 0 none, 1 bias[col*bstride], 2 bias[row*bstride]
//   SWZ: 1 = 1-D grid, z = bid % nz (XCD binding), GROUP_M=4 tile order
//   EXP: 1 = write exp(acc*scale), atomic col sums into colsum[bz*N+col];
//        stores staged through f32 A-LDS for coalesced 16B writes (needs CVT&1)
//   CVT bit0/bit1: A/B is f32 -> ASYNC-staged f32 LDS tile, converted on read
//   CSDIV: 1 = divide by colsum[bz*N+col]
// ---------------------------------------------------------------------------
template <typename OutT, int BIAS, int BN, int SWZ = 0, int EXP = 0, int CVT = 0,
          int CSDIV = 0, int TM = 4>
__global__ __launch_bounds__(256) void gemm_nt(
    const void* __restrict__ Av, const void* __restrict__ Bv,
    OutT* __restrict__ C, const float* __restrict__ bias, int bstride,
    float* __restrict__ colsum,
    int M, int N, int K, int ldA, int ldB,
    long long sA, long long sB, long long sC,
    float scale, int nz, int npn)
{
    constexpr int NF = BN / 32;              // B frags per wave (n-dir)
    constexpr int BM = TM * 32;              // tile rows
    constexpr bool AF = (CVT & 1) != 0, BF = (CVT & 2) != 0;
    static_assert(!EXP || (AF && BN == 128), "EXP epilogue reuses f32 A-LDS");
    __shared__ __align__(16) char AsRaw[AF ? BM * 64 * 4 : BM * 64 * 2];
    __shared__ __align__(16) char BsRaw[BF ? BN * 64 * 4 : BN * 64 * 2];
    bf16*  As  = (bf16*)AsRaw;   float* Asf = (float*)AsRaw;
    bf16*  Bs  = (bf16*)BsRaw;   float* Bsf = (float*)BsRaw;

    int bz, m0, n0;
    if constexpr (SWZ) {
        const int bid = blockIdx.x;
        bz = bid % nz;                        // bind batch -> XCD (round-robin)
        const int t0 = bid / nz;
        const int grp = t0 / (4 * npn);       // GROUP_M = 4
        m0 = (grp * 4 + (t0 % 4)) * BM;
        n0 = ((t0 / 4) % npn) * BN;
    } else {
        bz = blockIdx.z;
        m0 = blockIdx.y * BM;
        n0 = blockIdx.x * BN;
    }
    C += sC * bz;

    const bf16*  A16 = nullptr; const float* A32 = nullptr;
    const bf16*  B16 = nullptr; const float* B32 = nullptr;
    if constexpr (AF) A32 = (const float*)Av + sA * bz;
    else              A16 = (const bf16*)Av + sA * bz;
    if constexpr (BF) B32 = (const float*)Bv + sB * bz;
    else              B16 = (const bf16*)Bv + sB * bz;

    const int t = threadIdx.x;
    const int lane = t & 63;
    const int w = t >> 6;                    // wave id 0..3
    const int wm = (w >> 1) * (BM / 2);      // wave row offset
    const int wn = (w & 1) * (BN / 2);       // wave col offset

    f32x4 acc[TM][NF] = {};

    // bf16 staging: idx = c*256+t -> row = idx>>3, swizzle XOR-(row&7) on 8 chunks
    const int trow = t >> 3;
    const int tcol = (t & 7) ^ (trow & 7);
    // f32 staging: idx = c*256+t -> row = c*16 + (t>>4), swizzle XOR-(t>>4) on 16
    const int t16r = t >> 4;
    const int t16c = (t & 15) ^ t16r;
    char* stA = (char*)AsRaw + (size_t)w * 1024;   // + c*4096 (wave-uniform)
    char* stB = (char*)BsRaw + (size_t)w * 1024;

    for (int k0 = 0; k0 < K; k0 += 64) {
        __syncthreads();   // protect LDS while other waves still compute
        if constexpr (AF) {
            const float* a_src = A32 + (long long)(m0 + t16r) * ldA + k0 + t16c * 4;
#pragma unroll
            for (int c = 0; c < BM / 16; ++c)
                async_cp16(a_src + (long long)(c * 16) * ldA, stA + c * 4096);
        } else {
            const bf16* a_src = A16 + (long long)(m0 + trow) * ldA + k0 + tcol * 8;
#pragma unroll
            for (int c = 0; c < BM / 32; ++c)
                async_cp16(a_src + (long long)(c * 32) * ldA, stA + c * 4096);
        }
        if constexpr (BF) {
            const float* b_src = B32 + (long long)(n0 + t16r) * ldB + k0 + t16c * 4;
#pragma unroll
            for (int c = 0; c < BN / 16; ++c)
                async_cp16(b_src + (long long)(c * 16) * ldB, stB + c * 4096);
        } else {
            const bf16* b_src = B16 + (long long)(n0 + trow) * ldB + k0 + tcol * 8;
#pragma unroll
            for (int c = 0; c < NF; ++c)
                async_cp16(b_src + (long long)(c * 32) * ldB, stB + c * 4096);
        }
        __syncthreads();   // vmcnt drain before s_barrier

        const int rl = lane & 15;
        const int quad = lane >> 4;
        const int sw = rl & 7;
#pragma unroll
        for (int kk = 0; kk < 64; kk += 32) {
            const int c8 = (kk >> 3) + quad;          // bf16 logical chunk (8B)
            const int ko = ((c8 ^ sw) << 3);          // bf16 physical elem offset
            const int l0 = (kk >> 2) + quad * 2;      // f32 logical chunk (16B)
            s16x8 af[TM], bfr[NF];
#pragma unroll
            for (int i = 0; i < TM; ++i) {
                if constexpr (AF) {
                    const float* rp = Asf + (size_t)(wm + i * 16 + rl) * 64;
                    float4 f0 = *(const float4*)(rp + ((l0 ^ rl) << 2));
                    float4 f1 = *(const float4*)(rp + (((l0 + 1) ^ rl) << 2));
                    af[i] = pack8(f0, f1);
                } else {
                    af[i] = *(const s16x8*)(As + (wm + i * 16 + rl) * 64 + ko);
                }
            }
#pragma unroll
            for (int j = 0; j < NF; ++j) {
                if constexpr (BF) {
                    const float* rp = Bsf + (size_t)(wn + j * 16 + rl) * 64;
                    float4 f0 = *(const float4*)(rp + ((l0 ^ rl) << 2));
                    float4 f1 = *(const float4*)(rp + (((l0 + 1) ^ rl) << 2));
                    bfr[j] = pack8(f0, f1);
                } else {
                    bfr[j] = *(const s16x8*)(Bs + (wn + j * 16 + rl) * 64 + ko);
                }
            }
#pragma unroll
            for (int i = 0; i < TM; ++i)
#pragma unroll
                for (int j = 0; j < NF; ++j)
                    acc[i][j] = __builtin_amdgcn_mfma_f32_16x16x32_bf16(
                        af[i], bfr[j], acc[i][j], 0, 0, 0);
        }
    }

    // epilogue: D row = (lane>>4)*4 + r, col = lane&15  (verified m89/m91)
    const int cl = lane & 15;
    const int rquad = (lane >> 4) << 2;
    if constexpr (EXP) {
        // pass 1: exp in place + column sums + atomics
#pragma unroll
        for (int tn = 0; tn < NF; ++tn) {
            const int col = n0 + wn + tn * 16 + cl;
            float csum = 0.f;
#pragma unroll
            for (int tm = 0; tm < TM; ++tm) {
#pragma unroll
                for (int r = 0; r < 4; ++r) {
                    float v = __expf(acc[tm][tn][r] * scale);
                    acc[tm][tn][r] = v;
                    csum += v;
                }
            }
            csum += __shfl_xor(csum, 16);
            csum += __shfl_xor(csum, 32);
            if ((lane >> 4) == 0)
                atomicAdd(&colsum[(long long)bz * N + col], csum);
        }
        // pass 2: staged coalesced stores via f32 A-LDS (>= 32*132*4 B)
        float* Ls = (float*)AsRaw;
        const int srow = t >> 3;             // 0..31
        const int scol = (t & 7) * 16;       // 0..112
        const int grb = m0 + ((srow & 16) ? (BM / 2) : 0) + (srow & 15);
#pragma unroll
        for (int tm = 0; tm < TM; ++tm) {
            __syncthreads();                 // LDS free / prev pass read done
#pragma unroll
            for (int tn = 0; tn < NF; ++tn)
#pragma unroll
                for (int r = 0; r < 4; ++r)
                    Ls[((w >> 1) * 16 + rquad + r) * 132 + wn + tn * 16 + cl] =
                        acc[tm][tn][r];
            __syncthreads();
            float4 f0 = *(const float4*)&Ls[srow * 132 + scol];
            float4 f1 = *(const float4*)&Ls[srow * 132 + scol + 4];
            float4 f2 = *(const float4*)&Ls[srow * 132 + scol + 8];
            float4 f3 = *(const float4*)&Ls[srow * 132 + scol + 12];
            union { s16x8 v; uint4 u; } p0, p1;
            p0.v = pack8(f0, f1);  p1.v = pack8(f2, f3);
            uint4* dst = (uint4*)((bf16*)C + (long long)(grb + tm * 16) * N + n0 + scol);
            dst[0] = p0.u;
            dst[1] = p1.u;
        }
    } else {
#pragma unroll
        for (int tn = 0; tn < NF; ++tn) {
            const int col = n0 + wn + tn * 16 + cl;
            float bcol = 0.f;
            if constexpr (BIAS == 1) bcol = bias[(long long)col * bstride];
            float inv = 1.0f;
            if constexpr (CSDIV == 1) inv = 1.0f / colsum[(long long)bz * N + col];
#pragma unroll
            for (int tm = 0; tm < TM; ++tm) {
#pragma unroll
                for (int r = 0; r < 4; ++r) {
                    const int row = m0 + wm + tm * 16 + rquad + r;
                    float v = acc[tm][tn][r] * scale;
                    if constexpr (BIAS == 1) v += bcol;
                    if constexpr (BIAS == 2) v += bias[(long long)row * bstride];
                    if constexpr (CSDIV == 1) v *= inv;
                    storeC(C + (long long)row * N + col, v);
                }
            }
        }
    }
}

// ---------------------------------------------------------------------------
extern "C" void kernel_launch(void* const* d_in, const int* in_sizes, int n_in,
                              void* d_out, int out_size, void* d_ws, size_t ws_size,
                              hipStream_t stream)
{
    constexpr int Bb = 8, NK = 2048, NQ = 2048, D = 256, H = 1024;
    const float scale = 0.03125f;   // 1/sqrt(1024)
    constexpr size_t ES  = (size_t)NK * NQ;       // per-batch scores
    constexpr size_t ET  = (size_t)Bb * NK * D;   // T'/UnT elems (8.39 MB bf16)
    constexpr size_t FIX = 2 * ET * 2             // Tp + UnT
                         + (size_t)512 * 768 * 4  // Cbig
                         + (size_t)512 * 1024 * 2 // Abig (WqT | linb)
                         + (size_t)768 * 1024 * 2 // Bbig (WkT | WvT)
                         + (size_t)8 * NK * 4 + 1024;

    const float* KEY   = (const float*)d_in[0];
    const float* VALUE = (const float*)d_in[1];
    const float* QUERY = (const float*)d_in[2];
    const float* Wk_w  = (const float*)d_in[3];
    const float* Wk_b  = (const float*)d_in[4];
    const float* Wq_w  = (const float*)d_in[5];
    const float* Wq_b  = (const float*)d_in[6];   // cancels in softmax (unused)
    const float* Wv_w  = (const float*)d_in[7];
    const float* Wv_b  = (const float*)d_in[8];
    const float* lin_w = (const float*)d_in[9];
    const float* lin_b = (const float*)d_in[10];
    float* out = (float*)d_out;
    (void)Wq_b; (void)in_sizes; (void)n_in; (void)out_size;

    auto need = [&](int g) -> size_t { return FIX + (size_t)g * ES * 2; };
    const int g = (ws_size >= need(8)) ? 8 : (ws_size >= need(4)) ? 4 : 2;

    char* ws = (char*)d_ws;
    bf16* Sg   = (bf16*)ws;  ws += (size_t)g * ES * 2;     // STexp[k,i] per group
    bf16* Tp   = (bf16*)ws;  ws += ET * 2;                 // T' = KEY@G + vq
    bf16* UnT  = (bf16*)ws;  ws += ET * 2;                 // UnT[d, i] (transposed)
    float* Cbig= (float*)ws; ws += (size_t)512 * 768 * 4;  // [G|vq ; M2|c2]
    bf16* Abig = (bf16*)ws;  ws += (size_t)512 * 1024 * 2; // [WqT ; linb]
    bf16* Bbig = (bf16*)ws;  ws += (size_t)768 * 1024 * 2; // [WkT ; WvT]
    float* csm = (float*)ws; ws += (size_t)8 * NK * 4;     // column sums
    bf16* WqT  = Abig;
    bf16* linb = Abig + (size_t)256 * 1024;
    bf16* WkT  = Bbig;
    bf16* WvT  = Bbig + (size_t)384 * 1024;
    const float* C1  = Cbig;                               // G^T rows, vq at col 256
    const float* M2  = Cbig + (size_t)256 * 768 + 384;     // M2 rows, c2 at col 640
    const float* vq  = Cbig + 256;
    const float* c2  = Cbig + (size_t)256 * 768 + 640;

    dim3 blk(256);

    // 0: weight transposes + bias/pad rows + lin cvt + zero csm (one launch)
    prep_kernel<<<dim3(256, 5), blk, 0, stream>>>(
        Wk_w, Wk_b, Wq_w, Wv_w, Wv_b, lin_w, WkT, WqT, WvT, linb, csm);

    // 1: Cbig[512,768] = Abig @ Bbig^T (K=1024):
    //    rows 0..255  x cols 0..383   = [G^T | vq]  (WqT . WkT)
    //    rows 256..511 x cols 384..767 = [M2 | c2]  (lin_w . WvT)
    gemm_nt<float, 0, 128><<<dim3(6, 4, 1), blk, 0, stream>>>(
        Abig, Bbig, Cbig, nullptr, 1, nullptr, 512, 768, 1024, 1024, 1024,
        0, 0, 0, 1.0f, 1, 1);

    // 2: T'[i,e] = KEY[i,:] . G^T[e,:] + vq[e]   (A f32, B f32 w/ ldB=768; BN=64)
    gemm_nt<bf16, 1, 64, 0, 0, 3><<<dim3(4, 128, 1), blk, 0, stream>>>(
        KEY, C1, Tp, vq, 768, nullptr, Bb * NK, D, D, D, 768,
        0, 0, 0, 1.0f, 1, 1);

    // 3..5 per group of g batches
    for (int b0 = 0; b0 < Bb; b0 += g) {
        // 3: STexp[k,i] = exp(scale * QUERY[k,:].T'[i,:]), csm[i] += col sums
        //    TM=8: 256x128 tiles, 2x arithmetic intensity; coalesced stores
        gemm_nt<bf16, 0, 128, 1, 1, 1, 1, 8><<<dim3(g * (NQ / 256) * (NK / 128)), blk, 0, stream>>>(
            QUERY + (size_t)b0 * NQ * D, Tp + (size_t)b0 * NK * D, Sg,
            nullptr, 1, csm + (size_t)b0 * NK,
            NQ, NK, D, D, D,
            (long long)NQ * D, (long long)NK * D, (long long)NQ * NK, scale,
            g, NK / 128);
        // 4: UnT[d,i] = (M2[d,:] . VALUE[i,:] + c2[d]) / csm[i]   (BN=64)
        gemm_nt<bf16, 2, 64, 0, 0, 3, 1><<<dim3(g * NK / 64, 2, 1), blk, 0, stream>>>(
            M2, VALUE + (size_t)b0 * NK * D, UnT,
            c2, 768, csm + (size_t)b0 * NK,
            256, g * NK, D, 768, D,
            0, 0, 0, 1.0f, 1, 1);
        // 5: out[k,d] = STexp[k,:] . UnT[d,:]^T + lin_b[d]
        //    (B=UnT ldB=g*NK, per-batch column offset sB=NK; z=bid%g, BN=64)
        gemm_nt<float, 1, 64, 1><<<dim3(g * (NQ / 128) * (D / 64)), blk, 0, stream>>>(
            Sg, UnT, out + (size_t)b0 * NQ * D,
            lin_b, 1, nullptr,
            NQ, D, NK, NK, g * NK,
            (long long)NQ * NK, (long long)NK, (long long)NQ * D, 1.0f,
            g, D / 64);
    }
}

// Round 13
// 217.350 us; speedup vs baseline: 1.0993x; 1.0993x over previous
//
#include <hip/hip_runtime.h>
#include <hip/hip_bf16.h>

using bf16 = __hip_bfloat16;
typedef __attribute__((ext_vector_type(8))) short s16x8;   // 8 bf16 = 4 VGPRs
typedef __attribute__((ext_vector_type(4))) float f32x4;

// ---- async global->LDS 16B copy (wave-uniform LDS base + lane*16) ----
__device__ __forceinline__ void async_cp16(const void* g, void* lds) {
    __builtin_amdgcn_global_load_lds(
        (const __attribute__((address_space(1))) unsigned int*)g,
        (__attribute__((address_space(3))) unsigned int*)lds,
        16, 0, 0);
}

__device__ __forceinline__ void storeC(float* p, float v) { *p = v; }
__device__ __forceinline__ void storeC(bf16* p, float v) { *p = __float2bfloat16(v); }

// pack 8 f32 -> s16x8 bf16 fragment
__device__ __forceinline__ s16x8 pack8(float4 a, float4 b) {
    union { bf16 h[8]; s16x8 v; } o;
    o.h[0] = __float2bfloat16(a.x); o.h[1] = __float2bfloat16(a.y);
    o.h[2] = __float2bfloat16(a.z); o.h[3] = __float2bfloat16(a.w);
    o.h[4] = __float2bfloat16(b.x); o.h[5] = __float2bfloat16(b.y);
    o.h[6] = __float2bfloat16(b.z); o.h[7] = __float2bfloat16(b.w);
    return o.v;
}

// ---------------------------------------------------------------------------
// prep: y=0: WkT[384,1024] = [Wk_w^T ; Wk_b ; 0]
//       y=1: WqT[256,1024] = Wq_w^T
//       y=2: WvT[384,1024] = [Wv_w^T ; Wv_b ; 0]
//       y=3: linb[256,1024] = bf16(lin_w)   y=4: zero csm (16384 f32)
// ---------------------------------------------------------------------------
__global__ __launch_bounds__(256) void prep_kernel(
    const float* __restrict__ Wk_w, const float* __restrict__ Wk_b,
    const float* __restrict__ Wq_w,
    const float* __restrict__ Wv_w, const float* __restrict__ Wv_b,
    const float* __restrict__ lin_w,
    bf16* __restrict__ WkT, bf16* __restrict__ WqT, bf16* __restrict__ WvT,
    bf16* __restrict__ linb, float* __restrict__ csm)
{
    const int t = threadIdx.x, b = blockIdx.x, y = blockIdx.y;
    if (y <= 2) {
        const float* src = (y == 0) ? Wk_w : (y == 1) ? Wq_w : Wv_w;
        const float* bia = (y == 0) ? Wk_b : Wv_b;
        bf16* dst = (y == 0) ? WkT : (y == 1) ? WqT : WvT;
        if (b < 64) {                       // 64x64 transpose tiles (16 x 4)
            __shared__ float T[64][65];
            const int h0 = (b & 15) * 64, d0 = (b >> 4) * 64;
            const int r = t >> 2, cg = t & 3;
            const float* sp = src + (h0 + r) * 256 + d0 + cg * 16;
#pragma unroll
            for (int c4 = 0; c4 < 4; ++c4) {
                float4 v = *(const float4*)(sp + c4 * 4);
                const int cb = cg * 16 + c4 * 4;
                T[cb + 0][r] = v.x; T[cb + 1][r] = v.y;
                T[cb + 2][r] = v.z; T[cb + 3][r] = v.w;
            }
            __syncthreads();
            union { bf16 h[16]; uint4 u[2]; } o;
#pragma unroll
            for (int j = 0; j < 16; ++j) o.h[j] = __float2bfloat16(T[r][cg * 16 + j]);
            uint4* dp = (uint4*)(dst + (size_t)(d0 + r) * 1024 + h0 + cg * 16);
            dp[0] = o.u[0]; dp[1] = o.u[1];
        } else if (y != 1) {
            if (b < 68) {                   // row 256 = bias
                const int i = (b - 64) * 256 + t;
                dst[256 * 1024 + i] = __float2bfloat16(bia[i]);
            } else if (b < 132) {           // rows 257..383 = 0
                const int i = (b - 68) * 256 + t;
                if (i < 127 * 1024 / 8)
                    ((uint4*)(dst + 257 * 1024))[i] = uint4{0, 0, 0, 0};
            }
        }
    } else if (y == 3) {
        const int i = b * 256 + t;          // 65536 float4 groups
        float4 v = ((const float4*)lin_w)[i];
        union { bf16 h[4]; uint2 u; } o;
        o.h[0] = __float2bfloat16(v.x); o.h[1] = __float2bfloat16(v.y);
        o.h[2] = __float2bfloat16(v.z); o.h[3] = __float2bfloat16(v.w);
        ((uint2*)linb)[i] = o.u;
    } else {
        const int i = b * 256 + t;
        if (i < 4096) ((float4*)csm)[i] = float4{0.f, 0.f, 0.f, 0.f};
    }
}

// ---------------------------------------------------------------------------
// NT GEMM: C[M,N] = scale * (A[M,K] @ B[N,K]^T) + bias
//   Tile (TM*32)xBN, BK=64, 256 threads (4 waves), XOR-swizzled LDS
//   TM: m-frags per wave (2 -> 64-row tile, 4 -> 128-row tile)
//   BIAS: 0 none, 1 bias[col*bstride], 2 bias[row*bstride]
//   SWZ: 1 = 1-D grid, z = bid % nz (XCD binding), GROUP_M=4 tile order
//        (m varies fastest within a group -> B-tile reuse; group spans npn
//         n-tiles -> A-strip reuse)
//   EXP: 1 = write exp(acc*scale), atomic col sums into colsum[bz*N+col];
//        stores staged through f32 A-LDS for coalesced 16B writes (needs CVT&1)
//   CVT bit0/bit1: A/B is f32 -> ASYNC-staged f32 LDS tile, converted on read
//   CSDIV: 1 = divide by colsum[bz*N+col]
// ---------------------------------------------------------------------------
template <typename OutT, int BIAS, int BN, int SWZ = 0, int EXP = 0, int CVT = 0,
          int CSDIV = 0, int TM = 4>
__global__ __launch_bounds__(256) void gemm_nt(
    const void* __restrict__ Av, const void* __restrict__ Bv,
    OutT* __restrict__ C, const float* __restrict__ bias, int bstride,
    float* __restrict__ colsum,
    int M, int N, int K, int ldA, int ldB,
    long long sA, long long sB, long long sC,
    float scale, int nz, int npn)
{
    constexpr int NF = BN / 32;              // B frags per wave (n-dir)
    constexpr int BM = TM * 32;              // tile rows
    constexpr bool AF = (CVT & 1) != 0, BF = (CVT & 2) != 0;
    static_assert(!EXP || (AF && BN == 128 && TM == 4), "EXP epilogue layout");
    __shared__ __align__(16) char AsRaw[AF ? BM * 64 * 4 : BM * 64 * 2];
    __shared__ __align__(16) char BsRaw[BF ? BN * 64 * 4 : BN * 64 * 2];
    bf16*  As  = (bf16*)AsRaw;   float* Asf = (float*)AsRaw;
    bf16*  Bs  = (bf16*)BsRaw;   float* Bsf = (float*)BsRaw;

    int bz, m0, n0;
    if constexpr (SWZ) {
        const int bid = blockIdx.x;
        bz = bid % nz;                        // bind batch -> XCD (round-robin)
        const int t0 = bid / nz;
        const int grp = t0 / (4 * npn);       // GROUP_M = 4
        m0 = (grp * 4 + (t0 % 4)) * BM;
        n0 = ((t0 / 4) % npn) * BN;
    } else {
        bz = blockIdx.z;
        m0 = blockIdx.y * BM;
        n0 = blockIdx.x * BN;
    }
    C += sC * bz;

    const bf16*  A16 = nullptr; const float* A32 = nullptr;
    const bf16*  B16 = nullptr; const float* B32 = nullptr;
    if constexpr (AF) A32 = (const float*)Av + sA * bz;
    else              A16 = (const bf16*)Av + sA * bz;
    if constexpr (BF) B32 = (const float*)Bv + sB * bz;
    else              B16 = (const bf16*)Bv + sB * bz;

    const int t = threadIdx.x;
    const int lane = t & 63;
    const int w = t >> 6;                    // wave id 0..3
    const int wm = (w >> 1) * (BM / 2);      // wave row offset
    const int wn = (w & 1) * (BN / 2);       // wave col offset

    f32x4 acc[TM][NF] = {};

    // bf16 staging: idx = c*256+t -> row = idx>>3, swizzle XOR-(row&7) on 8 chunks
    const int trow = t >> 3;
    const int tcol = (t & 7) ^ (trow & 7);
    // f32 staging: idx = c*256+t -> row = c*16 + (t>>4), swizzle XOR-(t>>4) on 16
    const int t16r = t >> 4;
    const int t16c = (t & 15) ^ t16r;
    char* stA = (char*)AsRaw + (size_t)w * 1024;   // + c*4096 (wave-uniform)
    char* stB = (char*)BsRaw + (size_t)w * 1024;

    for (int k0 = 0; k0 < K; k0 += 64) {
        __syncthreads();   // protect LDS while other waves still compute
        if constexpr (AF) {
            const float* a_src = A32 + (long long)(m0 + t16r) * ldA + k0 + t16c * 4;
#pragma unroll
            for (int c = 0; c < BM / 16; ++c)
                async_cp16(a_src + (long long)(c * 16) * ldA, stA + c * 4096);
        } else {
            const bf16* a_src = A16 + (long long)(m0 + trow) * ldA + k0 + tcol * 8;
#pragma unroll
            for (int c = 0; c < BM / 32; ++c)
                async_cp16(a_src + (long long)(c * 32) * ldA, stA + c * 4096);
        }
        if constexpr (BF) {
            const float* b_src = B32 + (long long)(n0 + t16r) * ldB + k0 + t16c * 4;
#pragma unroll
            for (int c = 0; c < BN / 16; ++c)
                async_cp16(b_src + (long long)(c * 16) * ldB, stB + c * 4096);
        } else {
            const bf16* b_src = B16 + (long long)(n0 + trow) * ldB + k0 + tcol * 8;
#pragma unroll
            for (int c = 0; c < NF; ++c)
                async_cp16(b_src + (long long)(c * 32) * ldB, stB + c * 4096);
        }
        __syncthreads();   // vmcnt drain before s_barrier

        const int rl = lane & 15;
        const int quad = lane >> 4;
        const int sw = rl & 7;
#pragma unroll
        for (int kk = 0; kk < 64; kk += 32) {
            const int c8 = (kk >> 3) + quad;          // bf16 logical chunk (8B)
            const int ko = ((c8 ^ sw) << 3);          // bf16 physical elem offset
            const int l0 = (kk >> 2) + quad * 2;      // f32 logical chunk (16B)
            s16x8 af[TM], bfr[NF];
#pragma unroll
            for (int i = 0; i < TM; ++i) {
                if constexpr (AF) {
                    const float* rp = Asf + (size_t)(wm + i * 16 + rl) * 64;
                    float4 f0 = *(const float4*)(rp + ((l0 ^ rl) << 2));
                    float4 f1 = *(const float4*)(rp + (((l0 + 1) ^ rl) << 2));
                    af[i] = pack8(f0, f1);
                } else {
                    af[i] = *(const s16x8*)(As + (wm + i * 16 + rl) * 64 + ko);
                }
            }
#pragma unroll
            for (int j = 0; j < NF; ++j) {
                if constexpr (BF) {
                    const float* rp = Bsf + (size_t)(wn + j * 16 + rl) * 64;
                    float4 f0 = *(const float4*)(rp + ((l0 ^ rl) << 2));
                    float4 f1 = *(const float4*)(rp + (((l0 + 1) ^ rl) << 2));
                    bfr[j] = pack8(f0, f1);
                } else {
                    bfr[j] = *(const s16x8*)(Bs + (wn + j * 16 + rl) * 64 + ko);
                }
            }
#pragma unroll
            for (int i = 0; i < TM; ++i)
#pragma unroll
                for (int j = 0; j < NF; ++j)
                    acc[i][j] = __builtin_amdgcn_mfma_f32_16x16x32_bf16(
                        af[i], bfr[j], acc[i][j], 0, 0, 0);
        }
    }

    // epilogue: D row = (lane>>4)*4 + r, col = lane&15  (verified m89/m91)
    const int cl = lane & 15;
    const int rquad = (lane >> 4) << 2;
    if constexpr (EXP) {
        // pass 1: exp in place + column sums + atomics
#pragma unroll
        for (int tn = 0; tn < NF; ++tn) {
            const int col = n0 + wn + tn * 16 + cl;
            float csum = 0.f;
#pragma unroll
            for (int tm = 0; tm < TM; ++tm) {
#pragma unroll
                for (int r = 0; r < 4; ++r) {
                    float v = __expf(acc[tm][tn][r] * scale);
                    acc[tm][tn][r] = v;
                    csum += v;
                }
            }
            csum += __shfl_xor(csum, 16);
            csum += __shfl_xor(csum, 32);
            if ((lane >> 4) == 0)
                atomicAdd(&colsum[(long long)bz * N + col], csum);
        }
        // pass 2: staged coalesced stores via f32 A-LDS (>= 32*132*4 B)
        float* Ls = (float*)AsRaw;
        const int srow = t >> 3;             // 0..31
        const int scol = (t & 7) * 16;       // 0..112
        const int grb = m0 + ((srow & 16) ? (BM / 2) : 0) + (srow & 15);
#pragma unroll
        for (int tm = 0; tm < TM; ++tm) {
            __syncthreads();                 // LDS free / prev pass read done
#pragma unroll
            for (int tn = 0; tn < NF; ++tn)
#pragma unroll
                for (int r = 0; r < 4; ++r)
                    Ls[((w >> 1) * 16 + rquad + r) * 132 + wn + tn * 16 + cl] =
                        acc[tm][tn][r];
            __syncthreads();
            float4 f0 = *(const float4*)&Ls[srow * 132 + scol];
            float4 f1 = *(const float4*)&Ls[srow * 132 + scol + 4];
            float4 f2 = *(const float4*)&Ls[srow * 132 + scol + 8];
            float4 f3 = *(const float4*)&Ls[srow * 132 + scol + 12];
            union { s16x8 v; uint4 u; } p0, p1;
            p0.v = pack8(f0, f1);  p1.v = pack8(f2, f3);
            uint4* dst = (uint4*)((bf16*)C + (long long)(grb + tm * 16) * N + n0 + scol);
            dst[0] = p0.u;
            dst[1] = p1.u;
        }
    } else {
#pragma unroll
        for (int tn = 0; tn < NF; ++tn) {
            const int col = n0 + wn + tn * 16 + cl;
            float bcol = 0.f;
            if constexpr (BIAS == 1) bcol = bias[(long long)col * bstride];
            float inv = 1.0f;
            if constexpr (CSDIV == 1) inv = 1.0f / colsum[(long long)bz * N + col];
#pragma unroll
            for (int tm = 0; tm < TM; ++tm) {
#pragma unroll
                for (int r = 0; r < 4; ++r) {
                    const int row = m0 + wm + tm * 16 + rquad + r;
                    float v = acc[tm][tn][r] * scale;
                    if constexpr (BIAS == 1) v += bcol;
                    if constexpr (BIAS == 2) v += bias[(long long)row * bstride];
                    if constexpr (CSDIV == 1) v *= inv;
                    storeC(C + (long long)row * N + col, v);
                }
            }
        }
    }
}

// ---------------------------------------------------------------------------
extern "C" void kernel_launch(void* const* d_in, const int* in_sizes, int n_in,
                              void* d_out, int out_size, void* d_ws, size_t ws_size,
                              hipStream_t stream)
{
    constexpr int Bb = 8, NK = 2048, NQ = 2048, D = 256, H = 1024;
    const float scale = 0.03125f;   // 1/sqrt(1024)
    constexpr size_t ES  = (size_t)NK * NQ;       // per-batch scores
    constexpr size_t ET  = (size_t)Bb * NK * D;   // T'/UnT elems (8.39 MB bf16)
    constexpr size_t FIX = 2 * ET * 2             // Tp + UnT
                         + (size_t)512 * 768 * 4  // Cbig
                         + (size_t)512 * 1024 * 2 // Abig (WqT | linb)
                         + (size_t)768 * 1024 * 2 // Bbig (WkT | WvT)
                         + (size_t)8 * NK * 4 + 1024;

    const float* KEY   = (const float*)d_in[0];
    const float* VALUE = (const float*)d_in[1];
    const float* QUERY = (const float*)d_in[2];
    const float* Wk_w  = (const float*)d_in[3];
    const float* Wk_b  = (const float*)d_in[4];
    const float* Wq_w  = (const float*)d_in[5];
    const float* Wq_b  = (const float*)d_in[6];   // cancels in softmax (unused)
    const float* Wv_w  = (const float*)d_in[7];
    const float* Wv_b  = (const float*)d_in[8];
    const float* lin_w = (const float*)d_in[9];
    const float* lin_b = (const float*)d_in[10];
    float* out = (float*)d_out;
    (void)Wq_b; (void)in_sizes; (void)n_in; (void)out_size;

    auto need = [&](int g) -> size_t { return FIX + (size_t)g * ES * 2; };
    const int g = (ws_size >= need(8)) ? 8 : (ws_size >= need(4)) ? 4 : 2;

    char* ws = (char*)d_ws;
    bf16* Sg   = (bf16*)ws;  ws += (size_t)g * ES * 2;     // STexp[k,i] per group
    bf16* Tp   = (bf16*)ws;  ws += ET * 2;                 // T' = KEY@G + vq
    bf16* UnT  = (bf16*)ws;  ws += ET * 2;                 // UnT[d, i] (transposed)
    float* Cbig= (float*)ws; ws += (size_t)512 * 768 * 4;  // [G|vq ; M2|c2]
    bf16* Abig = (bf16*)ws;  ws += (size_t)512 * 1024 * 2; // [WqT ; linb]
    bf16* Bbig = (bf16*)ws;  ws += (size_t)768 * 1024 * 2; // [WkT ; WvT]
    float* csm = (float*)ws; ws += (size_t)8 * NK * 4;     // column sums
    bf16* WqT  = Abig;
    bf16* linb = Abig + (size_t)256 * 1024;
    bf16* WkT  = Bbig;
    bf16* WvT  = Bbig + (size_t)384 * 1024;
    const float* C1  = Cbig;                               // G^T rows, vq at col 256
    const float* M2  = Cbig + (size_t)256 * 768 + 384;     // M2 rows, c2 at col 640
    const float* vq  = Cbig + 256;
    const float* c2  = Cbig + (size_t)256 * 768 + 640;

    dim3 blk(256);

    // 0: weight transposes + bias/pad rows + lin cvt + zero csm (one launch)
    prep_kernel<<<dim3(256, 5), blk, 0, stream>>>(
        Wk_w, Wk_b, Wq_w, Wv_w, Wv_b, lin_w, WkT, WqT, WvT, linb, csm);

    // 1: Cbig[512,768] = Abig @ Bbig^T (K=1024):
    //    rows 0..255  x cols 0..383   = [G^T | vq]  (WqT . WkT)
    //    rows 256..511 x cols 384..767 = [M2 | c2]  (lin_w . WvT)
    gemm_nt<float, 0, 128><<<dim3(6, 4, 1), blk, 0, stream>>>(
        Abig, Bbig, Cbig, nullptr, 1, nullptr, 512, 768, 1024, 1024, 1024,
        0, 0, 0, 1.0f, 1, 1);

    // 2: T'[i,e] = KEY[i,:] . G^T[e,:] + vq[e]
    //    TM=2/BM=64: 1024 blocks = 4/CU; m-inner swizzle (KEY strip reuse)
    gemm_nt<bf16, 1, 64, 1, 0, 3, 0, 2><<<dim3(1024), blk, 0, stream>>>(
        KEY, C1, Tp, vq, 768, nullptr, Bb * NK, D, D, D, 768,
        0, 0, 0, 1.0f, 1, 4);

    // 3..5 per group of g batches
    for (int b0 = 0; b0 < Bb; b0 += g) {
        // 3: STexp[k,i] = exp(scale * QUERY[k,:].T'[i,:]), csm[i] += col sums
        //    TM=4 (R11-proven), coalesced LDS-staged stores
        gemm_nt<bf16, 0, 128, 1, 1, 1, 1, 4><<<dim3(g * (NQ / 128) * (NK / 128)), blk, 0, stream>>>(
            QUERY + (size_t)b0 * NQ * D, Tp + (size_t)b0 * NK * D, Sg,
            nullptr, 1, csm + (size_t)b0 * NK,
            NQ, NK, D, D, D,
            (long long)NQ * D, (long long)NK * D, (long long)NQ * NK, scale,
            g, NK / 128);
        // 4: UnT[d,i] = (M2[d,:] . VALUE[i,:] + c2[d]) / csm[i]
        //    TM=2: 1024 blocks; m-inner swizzle (VALUE B-tile read once)
        gemm_nt<bf16, 2, 64, 1, 0, 3, 1, 2><<<dim3((g * NK / 64) * 4), blk, 0, stream>>>(
            M2, VALUE + (size_t)b0 * NK * D, UnT,
            c2, 768, csm + (size_t)b0 * NK,
            256, g * NK, D, 768, D,
            0, 0, 0, 1.0f, 1, g * NK / 64);
        // 5: out[k,d] = STexp[k,:] . UnT[d,:]^T + lin_b[d]
        //    TM=2: g*128 blocks = 4/CU; nz=g XCD binding, Sg strip reuse
        gemm_nt<float, 1, 64, 1, 0, 0, 0, 2><<<dim3(g * (NQ / 64) * (D / 64)), blk, 0, stream>>>(
            Sg, UnT, out + (size_t)b0 * NQ * D,
            lin_b, 1, nullptr,
            NQ, D, NK, NK, g * NK,
            (long long)NQ * NK, (long long)NK, (long long)NQ * D, 1.0f,
            g, D / 64);
    }
}

// Round 14
// 213.078 us; speedup vs baseline: 1.1213x; 1.0200x over previous
//
#include <hip/hip_runtime.h>
#include <hip/hip_bf16.h>

using bf16 = __hip_bfloat16;
typedef __attribute__((ext_vector_type(8))) short s16x8;   // 8 bf16 = 4 VGPRs
typedef __attribute__((ext_vector_type(4))) float f32x4;

// ---- async global->LDS 16B copy (wave-uniform LDS base + lane*16) ----
__device__ __forceinline__ void async_cp16(const void* g, void* lds) {
    __builtin_amdgcn_global_load_lds(
        (const __attribute__((address_space(1))) unsigned int*)g,
        (__attribute__((address_space(3))) unsigned int*)lds,
        16, 0, 0);
}

__device__ __forceinline__ void storeC(float* p, float v) { *p = v; }
__device__ __forceinline__ void storeC(bf16* p, float v) { *p = __float2bfloat16(v); }

// pack 8 f32 -> s16x8 bf16 fragment
__device__ __forceinline__ s16x8 pack8(float4 a, float4 b) {
    union { bf16 h[8]; s16x8 v; } o;
    o.h[0] = __float2bfloat16(a.x); o.h[1] = __float2bfloat16(a.y);
    o.h[2] = __float2bfloat16(a.z); o.h[3] = __float2bfloat16(a.w);
    o.h[4] = __float2bfloat16(b.x); o.h[5] = __float2bfloat16(b.y);
    o.h[6] = __float2bfloat16(b.z); o.h[7] = __float2bfloat16(b.w);
    return o.v;
}

// ---------------------------------------------------------------------------
// prep: y=0: WkT[384,1024] = [Wk_w^T ; Wk_b ; 0]
//       y=1: WqT[256,1024] = Wq_w^T
//       y=2: WvT[384,1024] = [Wv_w^T ; Wv_b ; 0]
//       y=3: linb[256,1024] = bf16(lin_w)
//       y=4: zero csm (16384 f32) + zero Cbig (393216 f32, for split-K atomics)
// grid (384, 5) x 256 threads
// ---------------------------------------------------------------------------
__global__ __launch_bounds__(256) void prep_kernel(
    const float* __restrict__ Wk_w, const float* __restrict__ Wk_b,
    const float* __restrict__ Wq_w,
    const float* __restrict__ Wv_w, const float* __restrict__ Wv_b,
    const float* __restrict__ lin_w,
    bf16* __restrict__ WkT, bf16* __restrict__ WqT, bf16* __restrict__ WvT,
    bf16* __restrict__ linb, float* __restrict__ csm, float* __restrict__ Cbig)
{
    const int t = threadIdx.x, b = blockIdx.x, y = blockIdx.y;
    if (y <= 2) {
        const float* src = (y == 0) ? Wk_w : (y == 1) ? Wq_w : Wv_w;
        const float* bia = (y == 0) ? Wk_b : Wv_b;
        bf16* dst = (y == 0) ? WkT : (y == 1) ? WqT : WvT;
        if (b < 64) {                       // 64x64 transpose tiles (16 x 4)
            __shared__ float T[64][65];
            const int h0 = (b & 15) * 64, d0 = (b >> 4) * 64;
            const int r = t >> 2, cg = t & 3;
            const float* sp = src + (h0 + r) * 256 + d0 + cg * 16;
#pragma unroll
            for (int c4 = 0; c4 < 4; ++c4) {
                float4 v = *(const float4*)(sp + c4 * 4);
                const int cb = cg * 16 + c4 * 4;
                T[cb + 0][r] = v.x; T[cb + 1][r] = v.y;
                T[cb + 2][r] = v.z; T[cb + 3][r] = v.w;
            }
            __syncthreads();
            union { bf16 h[16]; uint4 u[2]; } o;
#pragma unroll
            for (int j = 0; j < 16; ++j) o.h[j] = __float2bfloat16(T[r][cg * 16 + j]);
            uint4* dp = (uint4*)(dst + (size_t)(d0 + r) * 1024 + h0 + cg * 16);
            dp[0] = o.u[0]; dp[1] = o.u[1];
        } else if (y != 1) {
            if (b < 68) {                   // row 256 = bias
                const int i = (b - 64) * 256 + t;
                dst[256 * 1024 + i] = __float2bfloat16(bia[i]);
            } else if (b < 132) {           // rows 257..383 = 0
                const int i = (b - 68) * 256 + t;
                if (i < 127 * 1024 / 8)
                    ((uint4*)(dst + 257 * 1024))[i] = uint4{0, 0, 0, 0};
            }
        }
    } else if (y == 3) {
        const int i = b * 256 + t;          // 65536 float4 groups
        if (i < 65536) {
            float4 v = ((const float4*)lin_w)[i];
            union { bf16 h[4]; uint2 u; } o;
            o.h[0] = __float2bfloat16(v.x); o.h[1] = __float2bfloat16(v.y);
            o.h[2] = __float2bfloat16(v.z); o.h[3] = __float2bfloat16(v.w);
            ((uint2*)linb)[i] = o.u;
        }
    } else {
        const int i = b * 256 + t;
        if (i < 4096) ((float4*)csm)[i] = float4{0.f, 0.f, 0.f, 0.f};
        if (i < 98304) ((float4*)Cbig)[i] = float4{0.f, 0.f, 0.f, 0.f};
    }
}

// ---------------------------------------------------------------------------
// NT GEMM: C[M,N] = scale * (A[M,K] @ B[N,K]^T) + bias
//   Tile (TM*32)xBN, BK in {64,128}, 256 threads (4 waves), XOR-swizzled LDS
//   BIAS: 0 none, 1 bias[col*bstride], 2 bias[row*bstride]
//   SWZ: 1 = 1-D grid, z = bid % nz (XCD binding), GROUP_M=4 tile order
//   EXP: 1 = exp(acc*scale) + atomic col sums; LDS-staged coalesced stores
//   CVT bit0/bit1: A/B is f32 -> ASYNC-staged f32 LDS tile, converted on read
//   CSDIV: 1 = divide by colsum[bz*N+col]
//   ATOM: 1 = atomicAdd f32 epilogue (split-K; C must be pre-zeroed)
// ---------------------------------------------------------------------------
template <typename OutT, int BIAS, int BN, int SWZ = 0, int EXP = 0, int CVT = 0,
          int CSDIV = 0, int TM = 4, int BK = 64, int ATOM = 0>
__global__ __launch_bounds__(256) void gemm_nt(
    const void* __restrict__ Av, const void* __restrict__ Bv,
    OutT* __restrict__ C, const float* __restrict__ bias, int bstride,
    float* __restrict__ colsum,
    int M, int N, int K, int ldA, int ldB,
    long long sA, long long sB, long long sC,
    float scale, int nz, int npn)
{
    constexpr int NF = BN / 32;              // B frags per wave (n-dir)
    constexpr int BM = TM * 32;              // tile rows
    constexpr bool AF = (CVT & 1) != 0, BF = (CVT & 2) != 0;
    constexpr int NC8 = BK / 8;              // bf16 16B chunks per row
    constexpr int NC4 = BK / 4;              // f32 16B chunks per row
    constexpr int RPC8 = 256 / NC8;          // rows staged per chunk-iter (bf16)
    constexpr int RPC4 = 256 / NC4;          // rows staged per chunk-iter (f32)
    static_assert(!EXP || (AF && BN == 128 && TM == 4 && BK == 64), "EXP layout");
    __shared__ __align__(16) char AsRaw[AF ? BM * BK * 4 : BM * BK * 2];
    __shared__ __align__(16) char BsRaw[BF ? BN * BK * 4 : BN * BK * 2];
    bf16*  As  = (bf16*)AsRaw;   float* Asf = (float*)AsRaw;
    bf16*  Bs  = (bf16*)BsRaw;   float* Bsf = (float*)BsRaw;

    int bz, m0, n0;
    if constexpr (SWZ) {
        const int bid = blockIdx.x;
        bz = bid % nz;                        // bind batch -> XCD (round-robin)
        const int t0 = bid / nz;
        const int grp = t0 / (4 * npn);       // GROUP_M = 4
        m0 = (grp * 4 + (t0 % 4)) * BM;
        n0 = ((t0 / 4) % npn) * BN;
    } else {
        bz = blockIdx.z;
        m0 = blockIdx.y * BM;
        n0 = blockIdx.x * BN;
    }
    C += sC * bz;

    const bf16*  A16 = nullptr; const float* A32 = nullptr;
    const bf16*  B16 = nullptr; const float* B32 = nullptr;
    if constexpr (AF) A32 = (const float*)Av + sA * bz;
    else              A16 = (const bf16*)Av + sA * bz;
    if constexpr (BF) B32 = (const float*)Bv + sB * bz;
    else              B16 = (const bf16*)Bv + sB * bz;

    const int t = threadIdx.x;
    const int lane = t & 63;
    const int w = t >> 6;                    // wave id 0..3
    const int wm = (w >> 1) * (BM / 2);      // wave row offset
    const int wn = (w & 1) * (BN / 2);       // wave col offset

    f32x4 acc[TM][NF] = {};

    // bf16 staging: rowLocal = t/NC8, col8' = (t%NC8) ^ (rowLocal%NC8)
    const int trow = t / NC8;
    const int tcol = (t % NC8) ^ (trow % NC8);
    // f32 staging: rowLocal = t/NC4, col4' = (t%NC4) ^ (rowLocal%NC4)
    const int t4r = t / NC4;
    const int t4c = (t % NC4) ^ (t4r % NC4);
    char* stA = (char*)AsRaw + (size_t)w * 1024;   // + c*4096 (wave-uniform)
    char* stB = (char*)BsRaw + (size_t)w * 1024;

    for (int k0 = 0; k0 < K; k0 += BK) {
        __syncthreads();   // protect LDS while other waves still compute
        if constexpr (AF) {
            const float* a_src = A32 + (long long)(m0 + t4r) * ldA + k0 + t4c * 4;
#pragma unroll
            for (int c = 0; c < BM / RPC4; ++c)
                async_cp16(a_src + (long long)(c * RPC4) * ldA, stA + c * 4096);
        } else {
            const bf16* a_src = A16 + (long long)(m0 + trow) * ldA + k0 + tcol * 8;
#pragma unroll
            for (int c = 0; c < BM / RPC8; ++c)
                async_cp16(a_src + (long long)(c * RPC8) * ldA, stA + c * 4096);
        }
        if constexpr (BF) {
            const float* b_src = B32 + (long long)(n0 + t4r) * ldB + k0 + t4c * 4;
#pragma unroll
            for (int c = 0; c < BN / RPC4; ++c)
                async_cp16(b_src + (long long)(c * RPC4) * ldB, stB + c * 4096);
        } else {
            const bf16* b_src = B16 + (long long)(n0 + trow) * ldB + k0 + tcol * 8;
#pragma unroll
            for (int c = 0; c < BN / RPC8; ++c)
                async_cp16(b_src + (long long)(c * RPC8) * ldB, stB + c * 4096);
        }
        __syncthreads();   // vmcnt drain before s_barrier

        const int rl = lane & 15;
        const int quad = lane >> 4;
#pragma unroll
        for (int kk = 0; kk < BK; kk += 32) {
            const int c8 = (kk >> 3) + quad;          // bf16 logical chunk (8B)
            const int ko = ((c8 ^ (rl & (NC8 - 1))) << 3);
            const int l0 = (kk >> 2) + quad * 2;      // f32 logical chunk (16B)
            const int k4 = rl & (NC4 - 1);
            s16x8 af[TM], bfr[NF];
#pragma unroll
            for (int i = 0; i < TM; ++i) {
                if constexpr (AF) {
                    const float* rp = Asf + (size_t)(wm + i * 16 + rl) * BK;
                    float4 f0 = *(const float4*)(rp + ((l0 ^ k4) << 2));
                    float4 f1 = *(const float4*)(rp + (((l0 + 1) ^ k4) << 2));
                    af[i] = pack8(f0, f1);
                } else {
                    af[i] = *(const s16x8*)(As + (size_t)(wm + i * 16 + rl) * BK + ko);
                }
            }
#pragma unroll
            for (int j = 0; j < NF; ++j) {
                if constexpr (BF) {
                    const float* rp = Bsf + (size_t)(wn + j * 16 + rl) * BK;
                    float4 f0 = *(const float4*)(rp + ((l0 ^ k4) << 2));
                    float4 f1 = *(const float4*)(rp + (((l0 + 1) ^ k4) << 2));
                    bfr[j] = pack8(f0, f1);
                } else {
                    bfr[j] = *(const s16x8*)(Bs + (size_t)(wn + j * 16 + rl) * BK + ko);
                }
            }
#pragma unroll
            for (int i = 0; i < TM; ++i)
#pragma unroll
                for (int j = 0; j < NF; ++j)
                    acc[i][j] = __builtin_amdgcn_mfma_f32_16x16x32_bf16(
                        af[i], bfr[j], acc[i][j], 0, 0, 0);
        }
    }

    // epilogue: D row = (lane>>4)*4 + r, col = lane&15  (verified m89/m91)
    const int cl = lane & 15;
    const int rquad = (lane >> 4) << 2;
    if constexpr (EXP) {
        // pass 1: exp in place + column sums + atomics
#pragma unroll
        for (int tn = 0; tn < NF; ++tn) {
            const int col = n0 + wn + tn * 16 + cl;
            float csum = 0.f;
#pragma unroll
            for (int tm = 0; tm < TM; ++tm) {
#pragma unroll
                for (int r = 0; r < 4; ++r) {
                    float v = __expf(acc[tm][tn][r] * scale);
                    acc[tm][tn][r] = v;
                    csum += v;
                }
            }
            csum += __shfl_xor(csum, 16);
            csum += __shfl_xor(csum, 32);
            if ((lane >> 4) == 0)
                atomicAdd(&colsum[(long long)bz * N + col], csum);
        }
        // pass 2: staged coalesced stores via f32 A-LDS (>= 32*132*4 B)
        float* Ls = (float*)AsRaw;
        const int srow = t >> 3;             // 0..31
        const int scol = (t & 7) * 16;       // 0..112
        const int grb = m0 + ((srow & 16) ? (BM / 2) : 0) + (srow & 15);
#pragma unroll
        for (int tm = 0; tm < TM; ++tm) {
            __syncthreads();                 // LDS free / prev pass read done
#pragma unroll
            for (int tn = 0; tn < NF; ++tn)
#pragma unroll
                for (int r = 0; r < 4; ++r)
                    Ls[((w >> 1) * 16 + rquad + r) * 132 + wn + tn * 16 + cl] =
                        acc[tm][tn][r];
            __syncthreads();
            float4 f0 = *(const float4*)&Ls[srow * 132 + scol];
            float4 f1 = *(const float4*)&Ls[srow * 132 + scol + 4];
            float4 f2 = *(const float4*)&Ls[srow * 132 + scol + 8];
            float4 f3 = *(const float4*)&Ls[srow * 132 + scol + 12];
            union { s16x8 v; uint4 u; } p0, p1;
            p0.v = pack8(f0, f1);  p1.v = pack8(f2, f3);
            uint4* dst = (uint4*)((bf16*)C + (long long)(grb + tm * 16) * N + n0 + scol);
            dst[0] = p0.u;
            dst[1] = p1.u;
        }
    } else {
#pragma unroll
        for (int tn = 0; tn < NF; ++tn) {
            const int col = n0 + wn + tn * 16 + cl;
            float bcol = 0.f;
            if constexpr (BIAS == 1) bcol = bias[(long long)col * bstride];
            float inv = 1.0f;
            if constexpr (CSDIV == 1) inv = 1.0f / colsum[(long long)bz * N + col];
#pragma unroll
            for (int tm = 0; tm < TM; ++tm) {
#pragma unroll
                for (int r = 0; r < 4; ++r) {
                    const int row = m0 + wm + tm * 16 + rquad + r;
                    float v = acc[tm][tn][r] * scale;
                    if constexpr (BIAS == 1) v += bcol;
                    if constexpr (BIAS == 2) v += bias[(long long)row * bstride];
                    if constexpr (CSDIV == 1) v *= inv;
                    if constexpr (ATOM)
                        atomicAdd((float*)C + (long long)row * N + col, v);
                    else
                        storeC(C + (long long)row * N + col, v);
                }
            }
        }
    }
}

// ---------------------------------------------------------------------------
extern "C" void kernel_launch(void* const* d_in, const int* in_sizes, int n_in,
                              void* d_out, int out_size, void* d_ws, size_t ws_size,
                              hipStream_t stream)
{
    constexpr int Bb = 8, NK = 2048, NQ = 2048, D = 256, H = 1024;
    const float scale = 0.03125f;   // 1/sqrt(1024)
    constexpr size_t ES  = (size_t)NK * NQ;       // per-batch scores
    constexpr size_t ET  = (size_t)Bb * NK * D;   // T'/UnT elems (8.39 MB bf16)
    constexpr size_t FIX = 2 * ET * 2             // Tp + UnT
                         + (size_t)512 * 768 * 4  // Cbig
                         + (size_t)512 * 1024 * 2 // Abig (WqT | linb)
                         + (size_t)768 * 1024 * 2 // Bbig (WkT | WvT)
                         + (size_t)8 * NK * 4 + 1024;

    const float* KEY   = (const float*)d_in[0];
    const float* VALUE = (const float*)d_in[1];
    const float* QUERY = (const float*)d_in[2];
    const float* Wk_w  = (const float*)d_in[3];
    const float* Wk_b  = (const float*)d_in[4];
    const float* Wq_w  = (const float*)d_in[5];
    const float* Wq_b  = (const float*)d_in[6];   // cancels in softmax (unused)
    const float* Wv_w  = (const float*)d_in[7];
    const float* Wv_b  = (const float*)d_in[8];
    const float* lin_w = (const float*)d_in[9];
    const float* lin_b = (const float*)d_in[10];
    float* out = (float*)d_out;
    (void)Wq_b; (void)in_sizes; (void)n_in; (void)out_size;

    auto need = [&](int g) -> size_t { return FIX + (size_t)g * ES * 2; };
    const int g = (ws_size >= need(8)) ? 8 : (ws_size >= need(4)) ? 4 : 2;

    char* ws = (char*)d_ws;
    bf16* Sg   = (bf16*)ws;  ws += (size_t)g * ES * 2;     // STexp[k,i] per group
    bf16* Tp   = (bf16*)ws;  ws += ET * 2;                 // T' = KEY@G + vq
    bf16* UnT  = (bf16*)ws;  ws += ET * 2;                 // UnT[d, i] (transposed)
    float* Cbig= (float*)ws; ws += (size_t)512 * 768 * 4;  // [G|vq ; M2|c2]
    bf16* Abig = (bf16*)ws;  ws += (size_t)512 * 1024 * 2; // [WqT ; linb]
    bf16* Bbig = (bf16*)ws;  ws += (size_t)768 * 1024 * 2; // [WkT ; WvT]
    float* csm = (float*)ws; ws += (size_t)8 * NK * 4;     // column sums
    bf16* WqT  = Abig;
    bf16* linb = Abig + (size_t)256 * 1024;
    bf16* WkT  = Bbig;
    bf16* WvT  = Bbig + (size_t)384 * 1024;
    const float* C1  = Cbig;                               // G^T rows, vq at col 256
    const float* M2  = Cbig + (size_t)256 * 768 + 384;     // M2 rows, c2 at col 640
    const float* vq  = Cbig + 256;
    const float* c2  = Cbig + (size_t)256 * 768 + 640;

    dim3 blk(256);

    // 0: weight transposes + bias/pad rows + lin cvt + zero csm/Cbig
    prep_kernel<<<dim3(384, 5), blk, 0, stream>>>(
        Wk_w, Wk_b, Wq_w, Wv_w, Wv_b, lin_w, WkT, WqT, WvT, linb, csm, Cbig);

    // 1: Cbig[512,768] += Abig @ Bbig^T, split-K 4x256 (atomicAdd, pre-zeroed)
    //    rows 0..255  x cols 0..383   = [G^T | vq]  (WqT . WkT)
    //    rows 256..511 x cols 384..767 = [M2 | c2]  (lin_w . WvT)
    gemm_nt<float, 0, 128, 0, 0, 0, 0, 4, 64, 1><<<dim3(6, 4, 4), blk, 0, stream>>>(
        Abig, Bbig, Cbig, nullptr, 1, nullptr, 512, 768, 256, 1024, 1024,
        256, 256, 0, 1.0f, 1, 1);

    // 2: T'[i,e] = KEY[i,:] . G^T[e,:] + vq[e]
    //    TM=2/BM=64: 1024 blocks = 4/CU; m-inner swizzle (KEY strip reuse)
    gemm_nt<bf16, 1, 64, 1, 0, 3, 0, 2><<<dim3(1024), blk, 0, stream>>>(
        KEY, C1, Tp, vq, 768, nullptr, Bb * NK, D, D, D, 768,
        0, 0, 0, 1.0f, 1, 4);

    // 3..5 per group of g batches
    for (int b0 = 0; b0 < Bb; b0 += g) {
        // 3: STexp[k,i] = exp(scale * QUERY[k,:].T'[i,:]), csm[i] += col sums
        //    TM=4/BK=64 (R11-proven), coalesced LDS-staged stores
        gemm_nt<bf16, 0, 128, 1, 1, 1, 1, 4><<<dim3(g * (NQ / 128) * (NK / 128)), blk, 0, stream>>>(
            QUERY + (size_t)b0 * NQ * D, Tp + (size_t)b0 * NK * D, Sg,
            nullptr, 1, csm + (size_t)b0 * NK,
            NQ, NK, D, D, D,
            (long long)NQ * D, (long long)NK * D, (long long)NQ * NK, scale,
            g, NK / 128);
        // 4: UnT[d,i] = (M2[d,:] . VALUE[i,:] + c2[d]) / csm[i]
        //    TM=2: 1024 blocks; m-inner swizzle (VALUE B-tile read once)
        gemm_nt<bf16, 2, 64, 1, 0, 3, 1, 2><<<dim3((g * NK / 64) * 4), blk, 0, stream>>>(
            M2, VALUE + (size_t)b0 * NK * D, UnT,
            c2, 768, csm + (size_t)b0 * NK,
            256, g * NK, D, 768, D,
            0, 0, 0, 1.0f, 1, g * NK / 64);
        // 5: out[k,d] = STexp[k,:] . UnT[d,:]^T + lin_b[d]
        //    TM=2/BK=128: half the barriers, 2x loads in flight; 4/CU resident
        gemm_nt<float, 1, 64, 1, 0, 0, 0, 2, 128><<<dim3(g * (NQ / 64) * (D / 64)), blk, 0, stream>>>(
            Sg, UnT, out + (size_t)b0 * NQ * D,
            lin_b, 1, nullptr,
            NQ, D, NK, NK, g * NK,
            (long long)NQ * NK, (long long)NK, (long long)NQ * D, 1.0f,
            g, D / 64);
    }
}

// Round 15
// 204.458 us; speedup vs baseline: 1.1686x; 1.0422x over previous
//
#include <hip/hip_runtime.h>
#include <hip/hip_bf16.h>

using bf16 = __hip_bfloat16;
typedef __attribute__((ext_vector_type(8))) short s16x8;   // 8 bf16 = 4 VGPRs
typedef __attribute__((ext_vector_type(4))) float f32x4;

// ---- async global->LDS 16B copy (wave-uniform LDS base + lane*16) ----
__device__ __forceinline__ void async_cp16(const void* g, void* lds) {
    __builtin_amdgcn_global_load_lds(
        (const __attribute__((address_space(1))) unsigned int*)g,
        (__attribute__((address_space(3))) unsigned int*)lds,
        16, 0, 0);
}

__device__ __forceinline__ void storeC(float* p, float v) { *p = v; }
__device__ __forceinline__ void storeC(bf16* p, float v) { *p = __float2bfloat16(v); }

// pack 8 f32 -> s16x8 bf16 fragment
__device__ __forceinline__ s16x8 pack8(float4 a, float4 b) {
    union { bf16 h[8]; s16x8 v; } o;
    o.h[0] = __float2bfloat16(a.x); o.h[1] = __float2bfloat16(a.y);
    o.h[2] = __float2bfloat16(a.z); o.h[3] = __float2bfloat16(a.w);
    o.h[4] = __float2bfloat16(b.x); o.h[5] = __float2bfloat16(b.y);
    o.h[6] = __float2bfloat16(b.z); o.h[7] = __float2bfloat16(b.w);
    return o.v;
}

// ---------------------------------------------------------------------------
// prep: y=0: WkT[384,1024] = [Wk_w^T ; Wk_b ; 0]
//       y=1: WqT[256,1024] = Wq_w^T
//       y=2: WvT[384,1024] = [Wv_w^T ; Wv_b ; 0]
//       y=3: linb[256,1024] = bf16(lin_w)
//       y=4: zero csm (16384 f32) + zero Cbig (393216 f32, split-K atomics)
// grid (384, 5) x 256 threads
// ---------------------------------------------------------------------------
__global__ __launch_bounds__(256) void prep_kernel(
    const float* __restrict__ Wk_w, const float* __restrict__ Wk_b,
    const float* __restrict__ Wq_w,
    const float* __restrict__ Wv_w, const float* __restrict__ Wv_b,
    const float* __restrict__ lin_w,
    bf16* __restrict__ WkT, bf16* __restrict__ WqT, bf16* __restrict__ WvT,
    bf16* __restrict__ linb, float* __restrict__ csm, float* __restrict__ Cbig)
{
    const int t = threadIdx.x, b = blockIdx.x, y = blockIdx.y;
    if (y <= 2) {
        const float* src = (y == 0) ? Wk_w : (y == 1) ? Wq_w : Wv_w;
        const float* bia = (y == 0) ? Wk_b : Wv_b;
        bf16* dst = (y == 0) ? WkT : (y == 1) ? WqT : WvT;
        if (b < 64) {                       // 64x64 transpose tiles (16 x 4)
            __shared__ float T[64][65];
            const int h0 = (b & 15) * 64, d0 = (b >> 4) * 64;
            const int r = t >> 2, cg = t & 3;
            const float* sp = src + (h0 + r) * 256 + d0 + cg * 16;
#pragma unroll
            for (int c4 = 0; c4 < 4; ++c4) {
                float4 v = *(const float4*)(sp + c4 * 4);
                const int cb = cg * 16 + c4 * 4;
                T[cb + 0][r] = v.x; T[cb + 1][r] = v.y;
                T[cb + 2][r] = v.z; T[cb + 3][r] = v.w;
            }
            __syncthreads();
            union { bf16 h[16]; uint4 u[2]; } o;
#pragma unroll
            for (int j = 0; j < 16; ++j) o.h[j] = __float2bfloat16(T[r][cg * 16 + j]);
            uint4* dp = (uint4*)(dst + (size_t)(d0 + r) * 1024 + h0 + cg * 16);
            dp[0] = o.u[0]; dp[1] = o.u[1];
        } else if (y != 1) {
            if (b < 68) {                   // row 256 = bias
                const int i = (b - 64) * 256 + t;
                dst[256 * 1024 + i] = __float2bfloat16(bia[i]);
            } else if (b < 132) {           // rows 257..383 = 0
                const int i = (b - 68) * 256 + t;
                if (i < 127 * 1024 / 8)
                    ((uint4*)(dst + 257 * 1024))[i] = uint4{0, 0, 0, 0};
            }
        }
    } else if (y == 3) {
        const int i = b * 256 + t;          // 65536 float4 groups
        if (i < 65536) {
            float4 v = ((const float4*)lin_w)[i];
            union { bf16 h[4]; uint2 u; } o;
            o.h[0] = __float2bfloat16(v.x); o.h[1] = __float2bfloat16(v.y);
            o.h[2] = __float2bfloat16(v.z); o.h[3] = __float2bfloat16(v.w);
            ((uint2*)linb)[i] = o.u;
        }
    } else {
        const int i = b * 256 + t;
        if (i < 4096) ((float4*)csm)[i] = float4{0.f, 0.f, 0.f, 0.f};
        if (i < 98304) ((float4*)Cbig)[i] = float4{0.f, 0.f, 0.f, 0.f};
    }
}

// ---------------------------------------------------------------------------
// NT GEMM: C[M,N] = scale * (A[M,K] @ B[N,K]^T) + bias
//   Tile (TM*32)xBN, BK in {64,128}, 256 threads (4 waves), XOR-swizzled LDS
//   Single merged LDS block: A at 0, B at ABYTES; EXP epilogue reuses base.
//   BIAS: 0 none, 1 bias[col*bstride], 2 bias[row*bstride]
//   SWZ: 1 = 1-D grid, z = bid % nz (XCD binding), GROUP_M=4 tile order;
//        blocks with bid >= nblk run a fused f32->bf16 streaming cvt
//        (xsrc -> xdst, 4 f32/thread) instead of GEMM work.
//   EXP: 1 = exp(acc*scale) + atomic col sums; LDS-staged coalesced stores
//   CVT bit0/bit1: A/B is f32 -> ASYNC-staged f32 LDS tile, converted on read
//   CSDIV: 1 = divide by colsum[bz*N+col]
//   ATOM: 1 = atomicAdd f32 epilogue (split-K; C must be pre-zeroed)
// ---------------------------------------------------------------------------
template <typename OutT, int BIAS, int BN, int SWZ = 0, int EXP = 0, int CVT = 0,
          int CSDIV = 0, int TM = 4, int BK = 64, int ATOM = 0>
__global__ __launch_bounds__(256) void gemm_nt(
    const void* __restrict__ Av, const void* __restrict__ Bv,
    OutT* __restrict__ C, const float* __restrict__ bias, int bstride,
    float* __restrict__ colsum,
    int M, int N, int K, int ldA, int ldB,
    long long sA, long long sB, long long sC,
    float scale, int nz, int npn,
    int nblk, const float* __restrict__ xsrc, bf16* __restrict__ xdst)
{
    constexpr int NF = BN / 32;              // B frags per wave (n-dir)
    constexpr int BM = TM * 32;              // tile rows
    constexpr bool AF = (CVT & 1) != 0, BF = (CVT & 2) != 0;
    constexpr int NC8 = BK / 8;              // bf16 16B chunks per row
    constexpr int NC4 = BK / 4;              // f32 16B chunks per row
    constexpr int RPC8 = 256 / NC8;          // rows staged per chunk-iter (bf16)
    constexpr int RPC4 = 256 / NC4;          // rows staged per chunk-iter (f32)
    constexpr size_t ABYTES = AF ? (size_t)BM * BK * 4 : (size_t)BM * BK * 2;
    constexpr size_t BBYTES = BF ? (size_t)BN * BK * 4 : (size_t)BN * BK * 2;
    constexpr size_t EPIB   = EXP ? (size_t)32 * 132 * 4 : 0;
    constexpr size_t LDSZ   = (ABYTES + BBYTES) > EPIB ? (ABYTES + BBYTES) : EPIB;
    static_assert(!EXP || (BN == 128 && TM == 4 && BK == 64), "EXP layout");
    __shared__ __align__(16) char LdsRaw[LDSZ];
    char* AsRaw = LdsRaw;
    char* BsRaw = LdsRaw + ABYTES;
    bf16*  As  = (bf16*)AsRaw;   float* Asf = (float*)AsRaw;
    bf16*  Bs  = (bf16*)BsRaw;   float* Bsf = (float*)BsRaw;

    const int t = threadIdx.x;

    int bz, m0, n0;
    if constexpr (SWZ) {
        const int bid = blockIdx.x;
        if (xdst != nullptr && bid >= nblk) {   // fused streaming cvt blocks
            const int i = (bid - nblk) * 256 + t;
            float4 v = ((const float4*)xsrc)[i];
            union { bf16 h[4]; uint2 u; } o;
            o.h[0] = __float2bfloat16(v.x); o.h[1] = __float2bfloat16(v.y);
            o.h[2] = __float2bfloat16(v.z); o.h[3] = __float2bfloat16(v.w);
            ((uint2*)xdst)[i] = o.u;
            return;
        }
        bz = bid % nz;                        // bind batch -> XCD (round-robin)
        const int t0 = bid / nz;
        const int grp = t0 / (4 * npn);       // GROUP_M = 4
        m0 = (grp * 4 + (t0 % 4)) * BM;
        n0 = ((t0 / 4) % npn) * BN;
    } else {
        bz = blockIdx.z;
        m0 = blockIdx.y * BM;
        n0 = blockIdx.x * BN;
    }
    C += sC * bz;

    const bf16*  A16 = nullptr; const float* A32 = nullptr;
    const bf16*  B16 = nullptr; const float* B32 = nullptr;
    if constexpr (AF) A32 = (const float*)Av + sA * bz;
    else              A16 = (const bf16*)Av + sA * bz;
    if constexpr (BF) B32 = (const float*)Bv + sB * bz;
    else              B16 = (const bf16*)Bv + sB * bz;

    const int lane = t & 63;
    const int w = t >> 6;                    // wave id 0..3
    const int wm = (w >> 1) * (BM / 2);      // wave row offset
    const int wn = (w & 1) * (BN / 2);       // wave col offset

    f32x4 acc[TM][NF] = {};

    // bf16 staging: rowLocal = t/NC8, col8' = (t%NC8) ^ (rowLocal%NC8)
    const int trow = t / NC8;
    const int tcol = (t % NC8) ^ (trow % NC8);
    // f32 staging: rowLocal = t/NC4, col4' = (t%NC4) ^ (rowLocal%NC4)
    const int t4r = t / NC4;
    const int t4c = (t % NC4) ^ (t4r % NC4);
    char* stA = AsRaw + (size_t)w * 1024;    // + c*4096 (wave-uniform)
    char* stB = BsRaw + (size_t)w * 1024;

    for (int k0 = 0; k0 < K; k0 += BK) {
        __syncthreads();   // protect LDS while other waves still compute
        if constexpr (AF) {
            const float* a_src = A32 + (long long)(m0 + t4r) * ldA + k0 + t4c * 4;
#pragma unroll
            for (int c = 0; c < BM / RPC4; ++c)
                async_cp16(a_src + (long long)(c * RPC4) * ldA, stA + c * 4096);
        } else {
            const bf16* a_src = A16 + (long long)(m0 + trow) * ldA + k0 + tcol * 8;
#pragma unroll
            for (int c = 0; c < BM / RPC8; ++c)
                async_cp16(a_src + (long long)(c * RPC8) * ldA, stA + c * 4096);
        }
        if constexpr (BF) {
            const float* b_src = B32 + (long long)(n0 + t4r) * ldB + k0 + t4c * 4;
#pragma unroll
            for (int c = 0; c < BN / RPC4; ++c)
                async_cp16(b_src + (long long)(c * RPC4) * ldB, stB + c * 4096);
        } else {
            const bf16* b_src = B16 + (long long)(n0 + trow) * ldB + k0 + tcol * 8;
#pragma unroll
            for (int c = 0; c < BN / RPC8; ++c)
                async_cp16(b_src + (long long)(c * RPC8) * ldB, stB + c * 4096);
        }
        __syncthreads();   // vmcnt drain before s_barrier

        const int rl = lane & 15;
        const int quad = lane >> 4;
#pragma unroll
        for (int kk = 0; kk < BK; kk += 32) {
            const int c8 = (kk >> 3) + quad;          // bf16 logical chunk (8B)
            const int ko = ((c8 ^ (rl & (NC8 - 1))) << 3);
            const int l0 = (kk >> 2) + quad * 2;      // f32 logical chunk (16B)
            const int k4 = rl & (NC4 - 1);
            s16x8 af[TM], bfr[NF];
#pragma unroll
            for (int i = 0; i < TM; ++i) {
                if constexpr (AF) {
                    const float* rp = Asf + (size_t)(wm + i * 16 + rl) * BK;
                    float4 f0 = *(const float4*)(rp + ((l0 ^ k4) << 2));
                    float4 f1 = *(const float4*)(rp + (((l0 + 1) ^ k4) << 2));
                    af[i] = pack8(f0, f1);
                } else {
                    af[i] = *(const s16x8*)(As + (size_t)(wm + i * 16 + rl) * BK + ko);
                }
            }
#pragma unroll
            for (int j = 0; j < NF; ++j) {
                if constexpr (BF) {
                    const float* rp = Bsf + (size_t)(wn + j * 16 + rl) * BK;
                    float4 f0 = *(const float4*)(rp + ((l0 ^ k4) << 2));
                    float4 f1 = *(const float4*)(rp + (((l0 + 1) ^ k4) << 2));
                    bfr[j] = pack8(f0, f1);
                } else {
                    bfr[j] = *(const s16x8*)(Bs + (size_t)(wn + j * 16 + rl) * BK + ko);
                }
            }
#pragma unroll
            for (int i = 0; i < TM; ++i)
#pragma unroll
                for (int j = 0; j < NF; ++j)
                    acc[i][j] = __builtin_amdgcn_mfma_f32_16x16x32_bf16(
                        af[i], bfr[j], acc[i][j], 0, 0, 0);
        }
    }

    // epilogue: D row = (lane>>4)*4 + r, col = lane&15  (verified m89/m91)
    const int cl = lane & 15;
    const int rquad = (lane >> 4) << 2;
    if constexpr (EXP) {
        // pass 1: exp in place + column sums + atomics
#pragma unroll
        for (int tn = 0; tn < NF; ++tn) {
            const int col = n0 + wn + tn * 16 + cl;
            float csum = 0.f;
#pragma unroll
            for (int tm = 0; tm < TM; ++tm) {
#pragma unroll
                for (int r = 0; r < 4; ++r) {
                    float v = __expf(acc[tm][tn][r] * scale);
                    acc[tm][tn][r] = v;
                    csum += v;
                }
            }
            csum += __shfl_xor(csum, 16);
            csum += __shfl_xor(csum, 32);
            if ((lane >> 4) == 0)
                atomicAdd(&colsum[(long long)bz * N + col], csum);
        }
        // pass 2: staged coalesced stores via merged LDS (32*132*4 B)
        float* Ls = (float*)LdsRaw;
        const int srow = t >> 3;             // 0..31
        const int scol = (t & 7) * 16;       // 0..112
        const int grb = m0 + ((srow & 16) ? (BM / 2) : 0) + (srow & 15);
#pragma unroll
        for (int tm = 0; tm < TM; ++tm) {
            __syncthreads();                 // LDS free / prev pass read done
#pragma unroll
            for (int tn = 0; tn < NF; ++tn)
#pragma unroll
                for (int r = 0; r < 4; ++r)
                    Ls[((w >> 1) * 16 + rquad + r) * 132 + wn + tn * 16 + cl] =
                        acc[tm][tn][r];
            __syncthreads();
            float4 f0 = *(const float4*)&Ls[srow * 132 + scol];
            float4 f1 = *(const float4*)&Ls[srow * 132 + scol + 4];
            float4 f2 = *(const float4*)&Ls[srow * 132 + scol + 8];
            float4 f3 = *(const float4*)&Ls[srow * 132 + scol + 12];
            union { s16x8 v; uint4 u; } p0, p1;
            p0.v = pack8(f0, f1);  p1.v = pack8(f2, f3);
            uint4* dst = (uint4*)((bf16*)C + (long long)(grb + tm * 16) * N + n0 + scol);
            dst[0] = p0.u;
            dst[1] = p1.u;
        }
    } else {
#pragma unroll
        for (int tn = 0; tn < NF; ++tn) {
            const int col = n0 + wn + tn * 16 + cl;
            float bcol = 0.f;
            if constexpr (BIAS == 1) bcol = bias[(long long)col * bstride];
            float inv = 1.0f;
            if constexpr (CSDIV == 1) inv = 1.0f / colsum[(long long)bz * N + col];
#pragma unroll
            for (int tm = 0; tm < TM; ++tm) {
#pragma unroll
                for (int r = 0; r < 4; ++r) {
                    const int row = m0 + wm + tm * 16 + rquad + r;
                    float v = acc[tm][tn][r] * scale;
                    if constexpr (BIAS == 1) v += bcol;
                    if constexpr (BIAS == 2) v += bias[(long long)row * bstride];
                    if constexpr (CSDIV == 1) v *= inv;
                    if constexpr (ATOM)
                        atomicAdd((float*)C + (long long)row * N + col, v);
                    else
                        storeC(C + (long long)row * N + col, v);
                }
            }
        }
    }
}

// ---------------------------------------------------------------------------
extern "C" void kernel_launch(void* const* d_in, const int* in_sizes, int n_in,
                              void* d_out, int out_size, void* d_ws, size_t ws_size,
                              hipStream_t stream)
{
    constexpr int Bb = 8, NK = 2048, NQ = 2048, D = 256, H = 1024;
    const float scale = 0.03125f;   // 1/sqrt(1024)
    constexpr size_t ES  = (size_t)NK * NQ;       // per-batch scores
    constexpr size_t ET  = (size_t)Bb * NK * D;   // T'/UnT/Qb elems (8.39M)
    constexpr size_t FIX = 3 * ET * 2             // Tp + UnT + Qb
                         + (size_t)512 * 768 * 4  // Cbig
                         + (size_t)512 * 1024 * 2 // Abig (WqT | linb)
                         + (size_t)768 * 1024 * 2 // Bbig (WkT | WvT)
                         + (size_t)8 * NK * 4 + 1024;

    const float* KEY   = (const float*)d_in[0];
    const float* VALUE = (const float*)d_in[1];
    const float* QUERY = (const float*)d_in[2];
    const float* Wk_w  = (const float*)d_in[3];
    const float* Wk_b  = (const float*)d_in[4];
    const float* Wq_w  = (const float*)d_in[5];
    const float* Wq_b  = (const float*)d_in[6];   // cancels in softmax (unused)
    const float* Wv_w  = (const float*)d_in[7];
    const float* Wv_b  = (const float*)d_in[8];
    const float* lin_w = (const float*)d_in[9];
    const float* lin_b = (const float*)d_in[10];
    float* out = (float*)d_out;
    (void)Wq_b; (void)in_sizes; (void)n_in; (void)out_size;

    auto need = [&](int g) -> size_t { return FIX + (size_t)g * ES * 2; };
    const int g = (ws_size >= need(8)) ? 8 : (ws_size >= need(4)) ? 4 : 2;

    char* ws = (char*)d_ws;
    bf16* Sg   = (bf16*)ws;  ws += (size_t)g * ES * 2;     // STexp[k,i] per group
    bf16* Tp   = (bf16*)ws;  ws += ET * 2;                 // T' = KEY@G + vq
    bf16* UnT  = (bf16*)ws;  ws += ET * 2;                 // UnT[d, i] (transposed)
    bf16* Qb   = (bf16*)ws;  ws += ET * 2;                 // bf16(QUERY)
    float* Cbig= (float*)ws; ws += (size_t)512 * 768 * 4;  // [G|vq ; M2|c2]
    bf16* Abig = (bf16*)ws;  ws += (size_t)512 * 1024 * 2; // [WqT ; linb]
    bf16* Bbig = (bf16*)ws;  ws += (size_t)768 * 1024 * 2; // [WkT ; WvT]
    float* csm = (float*)ws; ws += (size_t)8 * NK * 4;     // column sums
    bf16* WqT  = Abig;
    bf16* linb = Abig + (size_t)256 * 1024;
    bf16* WkT  = Bbig;
    bf16* WvT  = Bbig + (size_t)384 * 1024;
    const float* C1  = Cbig;                               // G^T rows, vq at col 256
    const float* M2  = Cbig + (size_t)256 * 768 + 384;     // M2 rows, c2 at col 640
    const float* vq  = Cbig + 256;
    const float* c2  = Cbig + (size_t)256 * 768 + 640;

    dim3 blk(256);

    // 0: weight transposes + bias/pad rows + lin cvt + zero csm/Cbig
    prep_kernel<<<dim3(384, 5), blk, 0, stream>>>(
        Wk_w, Wk_b, Wq_w, Wv_w, Wv_b, lin_w, WkT, WqT, WvT, linb, csm, Cbig);

    // 1: Cbig[512,768] += Abig @ Bbig^T, split-K 4x256 (atomicAdd, pre-zeroed)
    gemm_nt<float, 0, 128, 0, 0, 0, 0, 4, 64, 1><<<dim3(6, 4, 4), blk, 0, stream>>>(
        Abig, Bbig, Cbig, nullptr, 1, nullptr, 512, 768, 256, 1024, 1024,
        256, 256, 0, 1.0f, 1, 1, 0, nullptr, nullptr);

    // 2: T'[i,e] = KEY[i,:] . G^T[e,:] + vq[e]  (TM=2, 1024 GEMM blocks)
    //    + 4096 fused cvt blocks: Qb = bf16(QUERY)  (bit-identical to in-LDS cvt)
    gemm_nt<bf16, 1, 64, 1, 0, 3, 0, 2><<<dim3(1024 + 4096), blk, 0, stream>>>(
        KEY, C1, Tp, vq, 768, nullptr, Bb * NK, D, D, D, 768,
        0, 0, 0, 1.0f, 1, 4, 1024, QUERY, Qb);

    // 3..5 per group of g batches
    for (int b0 = 0; b0 < Bb; b0 += g) {
        // 3: STexp[k,i] = exp(scale * Qb[k,:].T'[i,:]), csm[i] += col sums
        //    all-bf16: LDS 32KB -> 5 blocks/CU (was 48KB/3); coalesced stores
        gemm_nt<bf16, 0, 128, 1, 1, 0, 0, 4><<<dim3(g * (NQ / 128) * (NK / 128)), blk, 0, stream>>>(
            Qb + (size_t)b0 * NQ * D, Tp + (size_t)b0 * NK * D, Sg,
            nullptr, 1, csm + (size_t)b0 * NK,
            NQ, NK, D, D, D,
            (long long)NQ * D, (long long)NK * D, (long long)NQ * NK, scale,
            g, NK / 128, g * (NQ / 128) * (NK / 128), nullptr, nullptr);
        // 4: UnT[d,i] = (M2[d,:] . VALUE[i,:] + c2[d]) / csm[i]
        gemm_nt<bf16, 2, 64, 1, 0, 3, 1, 2><<<dim3((g * NK / 64) * 4), blk, 0, stream>>>(
            M2, VALUE + (size_t)b0 * NK * D, UnT,
            c2, 768, csm + (size_t)b0 * NK,
            256, g * NK, D, 768, D,
            0, 0, 0, 1.0f, 1, g * NK / 64, (g * NK / 64) * 4, nullptr, nullptr);
        // 5: out[k,d] = STexp[k,:] . UnT[d,:]^T + lin_b[d]  (TM=2/BK=128)
        gemm_nt<float, 1, 64, 1, 0, 0, 0, 2, 128><<<dim3(g * (NQ / 64) * (D / 64)), blk, 0, stream>>>(
            Sg, UnT, out + (size_t)b0 * NQ * D,
            lin_b, 1, nullptr,
            NQ, D, NK, NK, g * NK,
            (long long)NQ * NK, (long long)NK, (long long)NQ * D, 1.0f,
            g, D / 64, g * (NQ / 64) * (D / 64), nullptr, nullptr);
    }
}